// Round 9
// baseline (5980.894 us; speedup 1.0000x reference)
//
#include <hip/hip_runtime.h>
#include <hip/hip_bf16.h>

#define NA 35
#define NM 18
#define NN 53
#define TT 48
#define HH 32
#define OUT_MEO_BASE (1024*35*32)

// Coarse scheduling fence: prevents the compiler from interleaving the LDS
// loads of adjacent barrier-free regions (ph4 / 5x gru3). Without it the
// scheduler batches ~150 live VGPRs across the region and the 128-cap from
// __launch_bounds__(.,2) turns that into per-step scratch spills (r6/r8:
// ~14 GB HBM scratch traffic). Semantics-neutral.
#define SCHED_FENCE() __builtin_amdgcn_sched_barrier(0)

typedef unsigned short u16;

__device__ __forceinline__ float bfu(u16 u){ return __uint_as_float(((unsigned)u)<<16); }
__device__ __forceinline__ float flo(unsigned u){ return __uint_as_float(u<<16); }
__device__ __forceinline__ float fhi(unsigned u){ return __uint_as_float(u & 0xFFFF0000u); }
__device__ __forceinline__ u16 cvtbf(float f){
  unsigned u = __float_as_uint(f);
  return (u16)((u + 0x7FFFu + ((u>>16)&1u)) >> 16);   // round-to-nearest-even
}
// dot of float4 with 4 packed bf16 (uint2)
__device__ __forceinline__ float dotw(float4 x, uint2 w){
  return x.x*flo(w.x) + x.y*fhi(w.x) + x.z*flo(w.y) + x.w*fhi(w.y);
}

struct Params {
  const void *X_aqi, *X_meo, *ctx, *adj, *adjn;
  const void *emb0,*emb1,*emb2,*emb3,*emb4,*emb5,*emb6,*emb7,*emb8;
  const void *Wxa,*Wxm,*Wua,*Wum;
  const void *a0,*a1,*a2,*a3;
  const void *wih_a,*whh_a,*bih_a,*bhh_a,*wih_m,*whh_m,*bih_m,*bhh_m;
  const int *Xae,*Xme;
  void* out;
};

__device__ __forceinline__ float ldf(const void* p, int i, bool isbf){
  return isbf ? bfu(((const u16*)p)[i]) : ((const float*)p)[i];
}
__device__ __forceinline__ u16 ldraw(const void* p, int i, bool isbf){
  return isbf ? ((const u16*)p)[i] : cvtbf(((const float*)p)[i]);
}

// ~74 KB static LDS -> 2 blocks/CU when VGPR <= 128 (r6/r7 evidence:
// VGPR=128 -> 8 waves/CU (occ 23%); VGPR=256 -> 4 waves/CU (occ 12%)).
struct __align__(16) Smem {
  alignas(16) u16   wbf[4][96*36];   // GRU weights bf16, row stride 36 u16 = 72 B (b64 reads, 2-way free)
  alignas(16) float gb[4][96];       // bih_a, bhh_a, bih_m, bhh_m (fp32)
  alignas(16) float Wxa[6*32], Wxm[4*32];
  alignas(16) float aAll[4][188];
  alignas(16) float embA[304];
  alignas(16) float ctxS[NN][2], ctxD[NN][2];
  alignas(16) float uSrc[2][2][14];
  alignas(16) float uDst[2][2][14];
  alignas(16) u16   biasE[NN*56];    // bf16: adj_norm*a[184] or -1e12
  alignas(16) float xin[NN*16];
  alignas(16) u16   attri_bf[32*60]; // transposed [d][n], bf16, stride 60 (b64 reads, 2-way free)
  alignas(16) float srcv[NN*2], dstv[NN*2];
  alignas(16) float p[NN*56];        // softmax numerators fp32 (b128 broadcast reads; cols 53-55 zeroed)
  alignas(16) float inv[56];
  alignas(16) float gx[NN*32];       // fp32, rows 128 B (b128 broadcast in ph5)
  alignas(16) float h[NN*32];        // fp32 hidden state
};

__global__ __launch_bounds__(256, 2)
void chgat_gru_kernel(Params p){
  __shared__ Smem sm;
  const int tid = threadIdx.x;
  const int b = blockIdx.x;

  // ---------- stage 0: dtype detection (adj is exactly {0,1}) ----------
  bool isbf = false;
  {
    const unsigned* aw = (const unsigned*)p.adj;
    for (int i=0;i<32;++i){
      unsigned w = aw[i];
      if (w != 0u && w != 0x3F800000u) isbf = true;
    }
  }

  // ---------- stage 1: stage constants into LDS ----------
  for (int idx=tid; idx<3072; idx+=256) sm.wbf[0][(idx>>5)*36+(idx&31)] = ldraw(p.wih_a, idx, isbf);
  for (int idx=tid; idx<3072; idx+=256) sm.wbf[1][(idx>>5)*36+(idx&31)] = ldraw(p.whh_a, idx, isbf);
  for (int idx=tid; idx<3072; idx+=256) sm.wbf[2][(idx>>5)*36+(idx&31)] = ldraw(p.wih_m, idx, isbf);
  for (int idx=tid; idx<3072; idx+=256) sm.wbf[3][(idx>>5)*36+(idx&31)] = ldraw(p.whh_m, idx, isbf);
  if (tid < 96){
    sm.gb[0][tid]=ldf(p.bih_a,tid,isbf); sm.gb[1][tid]=ldf(p.bhh_a,tid,isbf);
    sm.gb[2][tid]=ldf(p.bih_m,tid,isbf); sm.gb[3][tid]=ldf(p.bhh_m,tid,isbf);
  }
  if (tid < 192) sm.Wxa[tid] = ldf(p.Wxa, tid, isbf);
  if (tid < 128) sm.Wxm[tid] = ldf(p.Wxm, tid, isbf);
  if (tid < 185){
    sm.aAll[0][tid] = ldf(p.a0, tid, isbf);
    sm.aAll[1][tid] = ldf(p.a1, tid, isbf);
    sm.aAll[2][tid] = ldf(p.a2, tid, isbf);
    sm.aAll[3][tid] = ldf(p.a3, tid, isbf);
  }
  if (tid < 70)  sm.embA[tid]        = ldf(p.emb0, tid, isbf);
  if (tid < 26)  sm.embA[70+tid]     = ldf(p.emb1, tid, isbf);
  if (tid < 14)  sm.embA[96+tid]     = ldf(p.emb2, tid, isbf);
  if (tid < 48)  sm.embA[110+tid]    = ldf(p.emb3, tid, isbf);
  if (tid < 18)  sm.embA[158+tid]    = ldf(p.emb4, tid, isbf);
  if (tid < 36)  sm.embA[176+tid]    = ldf(p.emb5, tid, isbf);
  if (tid < 26)  sm.embA[212+tid]    = ldf(p.emb6, tid, isbf);
  if (tid < 14)  sm.embA[238+tid]    = ldf(p.emb7, tid, isbf);
  if (tid < 48)  sm.embA[252+tid]    = ldf(p.emb8, tid, isbf);
  for (int idx=tid; idx<NN*32; idx+=256) sm.h[idx] = 0.f;
  // zero pads read by b128/b64 tails (cols 53..55 of p, 53..59 of attri_bf)
  if (tid < 159){ int rr=tid/3, cc=53+tid%3; sm.p[rr*56+cc] = 0.f; }
  if (tid < 224){ int rr=tid/7, cc=53+tid%7; sm.attri_bf[rr*60+cc] = 0; }
  __syncthreads();

  // ---------- stage 2: batch-invariant attention constants ----------
  if (tid < 212){
    int i = tid>>2, v = tid&3, it = (i<NA)?0:1;
    float s = 0.f;
    if (v < 2){
      const float* ac = &sm.aAll[it*2+v][32];
      for (int c=0;c<60;++c) s += ldf(p.ctx, i*60+c, isbf)*ac[c];
      sm.ctxS[i][v] = s;
    } else {
      const float* ac = &sm.aAll[(v-2)*2+it][124];
      for (int c=0;c<60;++c) s += ldf(p.ctx, i*60+c, isbf)*ac[c];
      sm.ctxD[i][v-2] = s;
    }
  }
  if (tid < 112){
    // fold Wu into a: uSrc[it][v] = Wu[it] @ a[it*2+v][0:32]; uDst[it][v] = Wu[it] @ a[v*2+it][92:124]
    int u = tid;
    int it = u / 56, rem = u % 56;
    int sd = rem / 28, rem2 = rem % 28;
    int v = rem2 / 14, k = rem2 % 14;
    const void* Wu = it ? p.Wum : p.Wua;
    const float* av = sd ? &sm.aAll[v*2+it][92] : &sm.aAll[it*2+v][0];
    float s = 0.f;
    for (int kk=0;kk<32;++kk) s += ldf(Wu, k*32+kk, isbf)*av[kk];
    if (sd) sm.uDst[it][v][k] = s; else sm.uSrc[it][v][k] = s;
  }
  for (int idx=tid; idx<NN*NN; idx+=256){
    int i = idx/NN, j = idx - i*NN;
    int sel = ((i<NA)?0:2) + ((j<NA)?0:1);
    float ad = ldf(p.adj, idx, isbf);
    sm.biasE[i*56+j] = cvtbf((ad > 0.f) ? ldf(p.adjn, idx, isbf)*sm.aAll[sel][184] : -1e12f);
  }
  __syncthreads();

  // ---------- prefetch t=0 (512 slots over 256 threads) ----------
  float rv1 = 0.f, rv2r = 0.f; int rv2i = 0;
  {
    int bt = b*TT + 0;
    rv1 = (tid < 210) ? ldf(p.X_aqi, bt*210 + tid, isbf) : ldf(p.X_meo, bt*72 + tid - 210, isbf);
    if (tid < 26) rv2r = ldf(p.X_meo, bt*72 + tid + 46, isbf);
    else { int u = tid - 26; rv2i = (u < 140) ? p.Xae[bt*140 + u] : p.Xme[bt*90 + u - 140]; }
  }

  const int ng = tid >> 6;          // wave 0..3
  const int hs = (tid >> 5) & 1;    // half-wave
  const int ks = hs;                // ph5 k-half
  const int d  = tid & 31;          // dim
  const int k0 = ks*16;

  #pragma unroll 1
  for (int t=0; t<TT; ++t){
    // ---- ph0: scatter prefetched inputs into xin ----
    if (tid < 210) sm.xin[(tid/6)*16 + tid%6] = rv1;
    else { int q = tid-210; sm.xin[(NA + (q>>2))*16 + (q&3)] = rv1; }
    if (tid < 26){ int q = tid + 46; sm.xin[(NA + (q>>2))*16 + (q&3)] = rv2r; }
    else {
      int u = tid - 26;
      if (u < 140){
        int n = u>>2, e = u&3;
        int off = (e==0)?0:(e==1)?70:(e==2)?96:110;
        sm.xin[n*16 + 6 + 2*e]     = sm.embA[off + rv2i*2];
        sm.xin[n*16 + 6 + 2*e + 1] = sm.embA[off + rv2i*2 + 1];
      } else {
        int q = u - 140;
        int n = NA + q/5, e = q%5;
        int off = (e==0)?158:(e==1)?176:(e==2)?212:(e==3)?238:252;
        sm.xin[n*16 + 4 + 2*e]     = sm.embA[off + rv2i*2];
        sm.xin[n*16 + 4 + 2*e + 1] = sm.embA[off + rv2i*2 + 1];
      }
    }
    // prefetch t+1
    {
      int tn = (t < TT-1) ? t+1 : t;
      int bt = b*TT + tn;
      rv1 = (tid < 210) ? ldf(p.X_aqi, bt*210 + tid, isbf) : ldf(p.X_meo, bt*72 + tid - 210, isbf);
      if (tid < 26) rv2r = ldf(p.X_meo, bt*72 + tid + 46, isbf);
      else { int u = tid - 26; rv2i = (u < 140) ? p.Xae[bt*140 + u] : p.Xme[bt*90 + u - 140]; }
    }
    __syncthreads();   // (A) xin ready

    // ---- ph1: attri_t (bf16, transposed) + src/dst logits ----
    for (int it = tid; it < 1908; it += 256){
      if (it < 1696){
        int n = it>>5, dj = it&31;
        const float* x = &sm.xin[n*16];
        float at = 0.f;
        if (n < NA){
          #pragma unroll
          for (int k=0;k<6;++k) at += x[k]*sm.Wxa[k*32+dj];
        } else {
          #pragma unroll
          for (int k=0;k<4;++k) at += x[k]*sm.Wxm[k*32+dj];
        }
        sm.attri_bf[dj*60 + n] = cvtbf(at);
      } else {
        int u = it - 1696;
        int i = u>>2, v = u&3, it2 = (i<NA)?0:1;
        const float* x = &sm.xin[i*16];
        float sacc; const float* uv;
        if (v < 2){ sacc = sm.ctxS[i][v];   uv = sm.uSrc[it2][v]; }
        else      { sacc = sm.ctxD[i][v-2]; uv = sm.uDst[it2][v-2]; }
        #pragma unroll
        for (int k=0;k<14;++k) sacc += x[k]*uv[k];
        if (v < 2) sm.srcv[i*2+v] = sacc; else sm.dstv[i*2+(v-2)] = sacc;
      }
    }
    __syncthreads();   // (B) attri_t, srcv, dstv ready

    // ---- ph3: masked softmax rows (4 lanes/row; e staged in LDS) ----
    if (tid < 212){
      int i = tid>>2, l = tid&3, it2 = (i<NA)?0:1;
      float s0 = sm.srcv[i*2+0], s1 = sm.srcv[i*2+1];
      float mx = -3.0e38f;
      for (int j=l; j<NN; j+=4){
        float e = ((j<NA)? s0 : s1) + sm.dstv[j*2+it2] + bfu(sm.biasE[i*56+j]);
        e = (e >= 0.f) ? e : 0.2f*e;
        sm.p[i*56+j] = e;
        mx = fmaxf(mx, e);
      }
      mx = fmaxf(mx, __shfl_xor(mx,1,64));
      mx = fmaxf(mx, __shfl_xor(mx,2,64));
      float sum = 0.f;
      for (int j=l; j<NN; j+=4){
        float pe = __expf(sm.p[i*56+j] - mx);
        sm.p[i*56+j] = pe;
        sum += pe;
      }
      sum += __shfl_xor(sum,1,64);
      sum += __shfl_xor(sum,2,64);
      if (l == 0) sm.inv[i] = 1.0f/sum;
    }
    __syncthreads();   // (C) p, inv ready

    // ---- ph4: gx rows n = ng+4*(2r+hs) (n ≡ ng mod 4 -> same wave as ph5 reader) ----
    {
      const int nb = ng + 4*hs;   // rows nb, nb+8, ..., nb+48
      float c0=0.f,c1=0.f,c2=0.f,c3=0.f,c4=0.f,c5=0.f,c6=0.f;
      #pragma unroll
      for (int jc=0; jc<14; ++jc){
        uint2 ab = *(const uint2*)&sm.attri_bf[d*60 + jc*4];
        float a0=flo(ab.x), a1=fhi(ab.x), a2=flo(ab.y), a3=fhi(ab.y);
        const float* pc = &sm.p[jc*4];
        { float4 q=*(const float4*)&pc[(nb   )*56]; c0 += q.x*a0+q.y*a1+q.z*a2+q.w*a3; }
        { float4 q=*(const float4*)&pc[(nb+ 8)*56]; c1 += q.x*a0+q.y*a1+q.z*a2+q.w*a3; }
        { float4 q=*(const float4*)&pc[(nb+16)*56]; c2 += q.x*a0+q.y*a1+q.z*a2+q.w*a3; }
        { float4 q=*(const float4*)&pc[(nb+24)*56]; c3 += q.x*a0+q.y*a1+q.z*a2+q.w*a3; }
        { float4 q=*(const float4*)&pc[(nb+32)*56]; c4 += q.x*a0+q.y*a1+q.z*a2+q.w*a3; }
        { float4 q=*(const float4*)&pc[(nb+40)*56]; c5 += q.x*a0+q.y*a1+q.z*a2+q.w*a3; }
        if (nb+48 <= 52){ float4 q=*(const float4*)&pc[(nb+48)*56]; c6 += q.x*a0+q.y*a1+q.z*a2+q.w*a3; }
      }
      sm.gx[(nb   )*32+d] = c0*sm.inv[nb];
      sm.gx[(nb+ 8)*32+d] = c1*sm.inv[nb+8];
      sm.gx[(nb+16)*32+d] = c2*sm.inv[nb+16];
      sm.gx[(nb+24)*32+d] = c3*sm.inv[nb+24];
      sm.gx[(nb+32)*32+d] = c4*sm.inv[nb+32];
      sm.gx[(nb+40)*32+d] = c5*sm.inv[nb+40];
      if (nb+48 <= 52) sm.gx[(nb+48)*32+d] = c6*sm.inv[nb+48];
    }
    SCHED_FENCE();   // keep ph4's live range out of ph5's

    // ---- ph5: GRU; wave ng owns nodes ≡ ng (mod 4); sub-passes of ≤3 nodes,
    //      fenced apart so only ONE sub-pass's registers are live at a time ----
    {
      const bool last = (t == TT-1);
      auto gru3 = [&](const u16* __restrict__ wi, const u16* __restrict__ wh,
                      const float* __restrict__ bi, const float* __restrict__ bh,
                      int n0, int mcnt, long long ob0, bool dolast){
        float r0=0.f,z0=0.f,i0=0.f,g0=0.f;
        float r1=0.f,z1=0.f,i1=0.f,g1=0.f;
        float r2=0.f,z2=0.f,i2=0.f,g2=0.f;
        #pragma unroll
        for (int kc=0;kc<4;++kc){
          const int kk = k0 + kc*4;
          uint2 wir = *(const uint2*)&wi[( d   )*36+kk];
          uint2 wiz = *(const uint2*)&wi[(32+d)*36+kk];
          uint2 win = *(const uint2*)&wi[(64+d)*36+kk];
          uint2 vhr = *(const uint2*)&wh[( d   )*36+kk];
          uint2 vhz = *(const uint2*)&wh[(32+d)*36+kk];
          uint2 vhn = *(const uint2*)&wh[(64+d)*36+kk];
          {
            float4 x4 = *(const float4*)&sm.gx[(n0   )*32+kk];
            float4 h4 = *(const float4*)&sm.h [(n0   )*32+kk];
            r0 += dotw(x4,wir)+dotw(h4,vhr); z0 += dotw(x4,wiz)+dotw(h4,vhz);
            i0 += dotw(x4,win);              g0 += dotw(h4,vhn);
          }
          if (mcnt>1){
            float4 x4 = *(const float4*)&sm.gx[(n0+ 4)*32+kk];
            float4 h4 = *(const float4*)&sm.h [(n0+ 4)*32+kk];
            r1 += dotw(x4,wir)+dotw(h4,vhr); z1 += dotw(x4,wiz)+dotw(h4,vhz);
            i1 += dotw(x4,win);              g1 += dotw(h4,vhn);
          }
          if (mcnt>2){
            float4 x4 = *(const float4*)&sm.gx[(n0+ 8)*32+kk];
            float4 h4 = *(const float4*)&sm.h [(n0+ 8)*32+kk];
            r2 += dotw(x4,wir)+dotw(h4,vhr); z2 += dotw(x4,wiz)+dotw(h4,vhz);
            i2 += dotw(x4,win);              g2 += dotw(h4,vhn);
          }
        }
        // combine k-halves (mcnt is wave-uniform)
        r0+=__shfl_xor(r0,32,64); z0+=__shfl_xor(z0,32,64); i0+=__shfl_xor(i0,32,64); g0+=__shfl_xor(g0,32,64);
        if (mcnt>1){ r1+=__shfl_xor(r1,32,64); z1+=__shfl_xor(z1,32,64); i1+=__shfl_xor(i1,32,64); g1+=__shfl_xor(g1,32,64); }
        if (mcnt>2){ r2+=__shfl_xor(r2,32,64); z2+=__shfl_xor(z2,32,64); i2+=__shfl_xor(i2,32,64); g2+=__shfl_xor(g2,32,64); }
        if (ks == 0){
          float br = bi[d]+bh[d], bz = bi[32+d]+bh[32+d];
          float bin = bi[64+d], bhn = bh[64+d];
          {
            float hold = sm.h[(n0   )*32+d];
            float rr = 1.f/(1.f+__expf(-(r0+br)));
            float zz = 1.f/(1.f+__expf(-(z0+bz)));
            float pre = (i0+bin) + rr*(g0+bhn);
            float e2 = __expf(2.f*pre);
            float hnew = (1.f-zz)*(1.f - 2.f/(e2+1.f)) + zz*hold;
            sm.h[(n0   )*32+d] = hnew;
            if (dolast){ long long oi = ob0 + d;
              if (isbf) ((u16*)p.out)[oi] = cvtbf(hnew); else ((float*)p.out)[oi] = hnew; }
          }
          if (mcnt>1){
            float hold = sm.h[(n0+ 4)*32+d];
            float rr = 1.f/(1.f+__expf(-(r1+br)));
            float zz = 1.f/(1.f+__expf(-(z1+bz)));
            float pre = (i1+bin) + rr*(g1+bhn);
            float e2 = __expf(2.f*pre);
            float hnew = (1.f-zz)*(1.f - 2.f/(e2+1.f)) + zz*hold;
            sm.h[(n0+ 4)*32+d] = hnew;
            if (dolast){ long long oi = ob0 + 128 + d;
              if (isbf) ((u16*)p.out)[oi] = cvtbf(hnew); else ((float*)p.out)[oi] = hnew; }
          }
          if (mcnt>2){
            float hold = sm.h[(n0+ 8)*32+d];
            float rr = 1.f/(1.f+__expf(-(r2+br)));
            float zz = 1.f/(1.f+__expf(-(z2+bz)));
            float pre = (i2+bin) + rr*(g2+bhn);
            float e2 = __expf(2.f*pre);
            float hnew = (1.f-zz)*(1.f - 2.f/(e2+1.f)) + zz*hold;
            sm.h[(n0+ 8)*32+d] = hnew;
            if (dolast){ long long oi = ob0 + 256 + d;
              if (isbf) ((u16*)p.out)[oi] = cvtbf(hnew); else ((float*)p.out)[oi] = hnew; }
          }
        }
      };
      const long long bA = (long long)b*(NA*HH);
      const long long bM = (long long)OUT_MEO_BASE + (long long)b*(NM*HH);
      const int cntA = (ng<3)?9:8;                 // aqi nodes ng+4m, m<cntA
      gru3(sm.wbf[0], sm.wbf[1], sm.gb[0], sm.gb[1], ng,    3,      bA + (long long)ng*32,      last);
      SCHED_FENCE();
      gru3(sm.wbf[0], sm.wbf[1], sm.gb[0], sm.gb[1], ng+12, 3,      bA + (long long)(ng+12)*32, last);
      SCHED_FENCE();
      gru3(sm.wbf[0], sm.wbf[1], sm.gb[0], sm.gb[1], ng+24, cntA-6, bA + (long long)(ng+24)*32, last);
      SCHED_FENCE();
      const int n0m  = NA + ((ng+1)&3);            // meo nodes ≡ ng (mod 4)
      const int cntM = (ng==1 || ng==2) ? 4 : 5;   // 36..52 per wave
      gru3(sm.wbf[2], sm.wbf[3], sm.gb[2], sm.gb[3], n0m,    3,      bM + (long long)(n0m-NA)*32,    last);
      SCHED_FENCE();
      gru3(sm.wbf[2], sm.wbf[3], sm.gb[2], sm.gb[3], n0m+12, cntM-3, bM + (long long)(n0m-NA+12)*32, last);
    }
    // loop tail: ph0 writes xin only (disjoint); barrier (A) orders the rest.
  }
}

extern "C" void kernel_launch(void* const* d_in, const int* in_sizes, int n_in,
                              void* d_out, int out_size, void* d_ws, size_t ws_size,
                              hipStream_t stream){
  (void)in_sizes; (void)n_in; (void)d_ws; (void)ws_size; (void)out_size;
  Params p;
  p.X_aqi = d_in[0];
  p.X_meo = d_in[1];
  p.ctx   = d_in[2];
  p.adj   = d_in[3];
  p.adjn  = d_in[4];
  p.emb0 = d_in[5];  p.emb1 = d_in[6];
  p.emb2 = d_in[7];  p.emb3 = d_in[8];
  p.emb4 = d_in[9];  p.emb5 = d_in[10];
  p.emb6 = d_in[11]; p.emb7 = d_in[12];
  p.emb8 = d_in[13];
  p.Wxa = d_in[14]; p.Wxm = d_in[15];
  p.Wua = d_in[16]; p.Wum = d_in[17];
  p.a0 = d_in[18]; p.a1 = d_in[19];
  p.a2 = d_in[20]; p.a3 = d_in[21];
  p.wih_a = d_in[22]; p.whh_a = d_in[23];
  p.bih_a = d_in[24]; p.bhh_a = d_in[25];
  p.wih_m = d_in[26]; p.whh_m = d_in[27];
  p.bih_m = d_in[28]; p.bhh_m = d_in[29];
  p.Xae = (const int*)d_in[30];
  p.Xme = (const int*)d_in[31];
  p.out = d_out;
  hipLaunchKernelGGL(chgat_gru_kernel, dim3(1024), dim3(256), 0, stream, p);
}

// Round 10
// 2137.030 us; speedup vs baseline: 2.7987x; 2.7987x over previous
//
#include <hip/hip_runtime.h>
#include <hip/hip_bf16.h>

#define NA 35
#define NM 18
#define NN 53
#define TT 48
#define HH 32
#define OUT_MEO_BASE (1024*35*32)
#define XHS 72     // xh row stride in u16 (144 B: 16B-aligned, not a 128B multiple -> 2-way LDS conflicts only)

typedef unsigned short u16;
typedef __attribute__((ext_vector_type(8))) short s8v;   // 8 bf16 (4 VGPRs) MFMA A/B frag
typedef __attribute__((ext_vector_type(4))) float f4v;   // MFMA C/D frag

__device__ __forceinline__ float bfu(u16 u){ return __uint_as_float(((unsigned)u)<<16); }
__device__ __forceinline__ float flo(unsigned u){ return __uint_as_float(u<<16); }
__device__ __forceinline__ float fhi(unsigned u){ return __uint_as_float(u & 0xFFFF0000u); }
__device__ __forceinline__ u16 cvtbf(float f){
  unsigned u = __float_as_uint(f);
  return (u16)((u + 0x7FFFu + ((u>>16)&1u)) >> 16);   // round-to-nearest-even
}

struct Params {
  const void *X_aqi, *X_meo, *ctx, *adj, *adjn;
  const void *emb0,*emb1,*emb2,*emb3,*emb4,*emb5,*emb6,*emb7,*emb8;
  const void *Wxa,*Wxm,*Wua,*Wum;
  const void *a0,*a1,*a2,*a3;
  const void *wih_a,*whh_a,*bih_a,*bhh_a,*wih_m,*whh_m,*bih_m,*bhh_m;
  const int *Xae,*Xme;
  void* out;
};

__device__ __forceinline__ float ldf(const void* p, int i, bool isbf){
  return isbf ? bfu(((const u16*)p)[i]) : ((const float*)p)[i];
}
__device__ __forceinline__ u16 ldraw(const void* p, int i, bool isbf){
  return isbf ? ((const u16*)p)[i] : cvtbf(((const float*)p)[i]);
}

// ~50 KB static LDS. GRU weights now live in per-wave REGISTER B-fragments
// (loaded once from global), so wbf/gx are gone; xh is the bf16 A-operand.
struct __align__(16) Smem {
  alignas(16) float gb[4][96];       // bih_a, bhh_a, bih_m, bhh_m (fp32)
  alignas(16) float Wxa[6*32], Wxm[4*32];
  alignas(16) float aAll[4][188];
  alignas(16) float embA[304];
  alignas(16) float ctxS[NN][2], ctxD[NN][2];
  alignas(16) float uSrc[2][2][14];
  alignas(16) float uDst[2][2][14];
  alignas(16) u16   biasE[NN*56];    // bf16: adj_norm*a[184] or -1e12
  alignas(16) float xin[NN*16];
  alignas(16) u16   attri_bf[32*60]; // transposed [d][n], bf16, stride 60
  alignas(16) float srcv[NN*2], dstv[NN*2];
  alignas(16) float p[NN*56];        // softmax numerators fp32 (cols 53-55 zeroed)
  alignas(16) float inv[56];
  alignas(16) u16   xh[64*XHS];      // MFMA A operand: [row n][0:32)=gx bf16, [32:64)=h bf16; rows 53-63 + cols 64-71 zero
  alignas(16) float h[NN*32];        // fp32 hidden state (carry precision)
};

// UNCAPPED launch bounds: the (.,2) 128-VGPR cap produced mandatory scratch
// spills (~14 GB HBM) in r6/r8/r9 regardless of source-level dieting.
// r7 proved 256-VGPR/4-waves-per-CU runs spill-free.
__global__ __launch_bounds__(256)
void chgat_gru_kernel(Params p){
  __shared__ Smem sm;
  const int tid = threadIdx.x;
  const int b = blockIdx.x;

  // ---------- stage 0: dtype detection (adj is exactly {0,1}) ----------
  bool isbf = false;
  {
    const unsigned* aw = (const unsigned*)p.adj;
    for (int i=0;i<32;++i){
      unsigned w = aw[i];
      if (w != 0u && w != 0x3F800000u) isbf = true;
    }
  }

  // ---------- stage 1: stage constants into LDS ----------
  if (tid < 96){
    sm.gb[0][tid]=ldf(p.bih_a,tid,isbf); sm.gb[1][tid]=ldf(p.bhh_a,tid,isbf);
    sm.gb[2][tid]=ldf(p.bih_m,tid,isbf); sm.gb[3][tid]=ldf(p.bhh_m,tid,isbf);
  }
  if (tid < 192) sm.Wxa[tid] = ldf(p.Wxa, tid, isbf);
  if (tid < 128) sm.Wxm[tid] = ldf(p.Wxm, tid, isbf);
  if (tid < 185){
    sm.aAll[0][tid] = ldf(p.a0, tid, isbf);
    sm.aAll[1][tid] = ldf(p.a1, tid, isbf);
    sm.aAll[2][tid] = ldf(p.a2, tid, isbf);
    sm.aAll[3][tid] = ldf(p.a3, tid, isbf);
  }
  if (tid < 70)  sm.embA[tid]        = ldf(p.emb0, tid, isbf);
  if (tid < 26)  sm.embA[70+tid]     = ldf(p.emb1, tid, isbf);
  if (tid < 14)  sm.embA[96+tid]     = ldf(p.emb2, tid, isbf);
  if (tid < 48)  sm.embA[110+tid]    = ldf(p.emb3, tid, isbf);
  if (tid < 18)  sm.embA[158+tid]    = ldf(p.emb4, tid, isbf);
  if (tid < 36)  sm.embA[176+tid]    = ldf(p.emb5, tid, isbf);
  if (tid < 26)  sm.embA[212+tid]    = ldf(p.emb6, tid, isbf);
  if (tid < 14)  sm.embA[238+tid]    = ldf(p.emb7, tid, isbf);
  if (tid < 48)  sm.embA[252+tid]    = ldf(p.emb8, tid, isbf);
  for (int idx=tid; idx<NN*32; idx+=256) sm.h[idx] = 0.f;
  for (int idx=tid; idx<64*XHS; idx+=256) sm.xh[idx] = 0;   // h=0 at t=0; pad rows/cols stay 0
  if (tid < 159){ int rr=tid/3, cc=53+tid%3; sm.p[rr*56+cc] = 0.f; }
  if (tid < 224){ int rr=tid/7, cc=53+tid%7; sm.attri_bf[rr*60+cc] = 0; }
  __syncthreads();

  // ---------- stage 2: batch-invariant attention constants ----------
  if (tid < 212){
    int i = tid>>2, v = tid&3, it = (i<NA)?0:1;
    float s = 0.f;
    if (v < 2){
      const float* ac = &sm.aAll[it*2+v][32];
      for (int c=0;c<60;++c) s += ldf(p.ctx, i*60+c, isbf)*ac[c];
      sm.ctxS[i][v] = s;
    } else {
      const float* ac = &sm.aAll[(v-2)*2+it][124];
      for (int c=0;c<60;++c) s += ldf(p.ctx, i*60+c, isbf)*ac[c];
      sm.ctxD[i][v-2] = s;
    }
  }
  if (tid < 112){
    int u = tid;
    int it = u / 56, rem = u % 56;
    int sd = rem / 28, rem2 = rem % 28;
    int v = rem2 / 14, k = rem2 % 14;
    const void* Wu = it ? p.Wum : p.Wua;
    const float* av = sd ? &sm.aAll[v*2+it][92] : &sm.aAll[it*2+v][0];
    float s = 0.f;
    for (int kk=0;kk<32;++kk) s += ldf(Wu, k*32+kk, isbf)*av[kk];
    if (sd) sm.uDst[it][v][k] = s; else sm.uSrc[it][v][k] = s;
  }
  for (int idx=tid; idx<NN*NN; idx+=256){
    int i = idx/NN, j = idx - i*NN;
    int sel = ((i<NA)?0:2) + ((j<NA)?0:1);
    float ad = ldf(p.adj, idx, isbf);
    sm.biasE[i*56+j] = cvtbf((ad > 0.f) ? ldf(p.adjn, idx, isbf)*sm.aAll[sel][184] : -1e12f);
  }
  __syncthreads();

  const int ng   = tid >> 6;        // wave 0..3
  const int hs   = (tid >> 5) & 1;  // half-wave (ph4)
  const int d    = tid & 31;        // dim (ph4)
  const int lane = tid & 63;
  const int nl   = lane & 15;       // MFMA col/row-in-tile index
  const int qd   = lane >> 4;       // MFMA quad

  // ---------- build per-wave persistent B-fragments (weights, once) ----------
  // B is [64 k][128 n]: n-groups r(0:32) z(32:64) i(64:96) g(96:128).
  // i-cols zero for k>=32 (h rows); g-cols zero for k<32 (x rows).
  // Fragment layout: lane holds B[k=qd*8+j + 32*ks][n = nt*16 + nl].
  // Waves 0-2: aqi weights; wave 3: meo (its both M-passes are meo).
  const int wty = (ng==3) ? 1 : 0;
  const void* wih_g = wty ? p.wih_m : p.wih_a;
  const void* whh_g = wty ? p.whh_m : p.whh_a;
  s8v bfr[16];
  #pragma unroll
  for (int nt=0; nt<8; ++nt){
    #pragma unroll
    for (int kst=0; kst<2; ++kst){
      s8v v;
      #pragma unroll
      for (int j=0; j<8; ++j){
        int n = nt*16 + nl;
        int k = kst*32 + qd*8 + j;
        int g2 = n>>5, dim = n&31;
        u16 val;
        if      (g2==0) val = (k<32) ? ldraw(wih_g, dim*32+k, isbf)       : ldraw(whh_g, dim*32+(k-32), isbf);
        else if (g2==1) val = (k<32) ? ldraw(wih_g, (32+dim)*32+k, isbf)  : ldraw(whh_g, (32+dim)*32+(k-32), isbf);
        else if (g2==2) val = (k<32) ? ldraw(wih_g, (64+dim)*32+k, isbf)  : (u16)0;
        else            val = (k<32) ? (u16)0                             : ldraw(whh_g, (64+dim)*32+(k-32), isbf);
        v[j] = (short)val;
      }
      bfr[nt*2+kst] = v;
    }
  }

  // ---------- prefetch t=0 (512 slots over 256 threads) ----------
  float rv1 = 0.f, rv2r = 0.f; int rv2i = 0;
  {
    int bt = b*TT + 0;
    rv1 = (tid < 210) ? ldf(p.X_aqi, bt*210 + tid, isbf) : ldf(p.X_meo, bt*72 + tid - 210, isbf);
    if (tid < 26) rv2r = ldf(p.X_meo, bt*72 + tid + 46, isbf);
    else { int u = tid - 26; rv2i = (u < 140) ? p.Xae[bt*140 + u] : p.Xme[bt*90 + u - 140]; }
  }

  #pragma unroll 1
  for (int t=0; t<TT; ++t){
    // ---- ph0: scatter prefetched inputs into xin ----
    if (tid < 210) sm.xin[(tid/6)*16 + tid%6] = rv1;
    else { int q = tid-210; sm.xin[(NA + (q>>2))*16 + (q&3)] = rv1; }
    if (tid < 26){ int q = tid + 46; sm.xin[(NA + (q>>2))*16 + (q&3)] = rv2r; }
    else {
      int u = tid - 26;
      if (u < 140){
        int n = u>>2, e = u&3;
        int off = (e==0)?0:(e==1)?70:(e==2)?96:110;
        sm.xin[n*16 + 6 + 2*e]     = sm.embA[off + rv2i*2];
        sm.xin[n*16 + 6 + 2*e + 1] = sm.embA[off + rv2i*2 + 1];
      } else {
        int q = u - 140;
        int n = NA + q/5, e = q%5;
        int off = (e==0)?158:(e==1)?176:(e==2)?212:(e==3)?238:252;
        sm.xin[n*16 + 4 + 2*e]     = sm.embA[off + rv2i*2];
        sm.xin[n*16 + 4 + 2*e + 1] = sm.embA[off + rv2i*2 + 1];
      }
    }
    // prefetch t+1
    {
      int tn = (t < TT-1) ? t+1 : t;
      int bt = b*TT + tn;
      rv1 = (tid < 210) ? ldf(p.X_aqi, bt*210 + tid, isbf) : ldf(p.X_meo, bt*72 + tid - 210, isbf);
      if (tid < 26) rv2r = ldf(p.X_meo, bt*72 + tid + 46, isbf);
      else { int u = tid - 26; rv2i = (u < 140) ? p.Xae[bt*140 + u] : p.Xme[bt*90 + u - 140]; }
    }
    __syncthreads();   // (A) xin ready; prior-step h writes visible to all waves

    // ---- ph1: attri_t (bf16, transposed) + src/dst logits ----
    for (int it = tid; it < 1908; it += 256){
      if (it < 1696){
        int n = it>>5, dj = it&31;
        const float* x = &sm.xin[n*16];
        float at = 0.f;
        if (n < NA){
          #pragma unroll
          for (int k=0;k<6;++k) at += x[k]*sm.Wxa[k*32+dj];
        } else {
          #pragma unroll
          for (int k=0;k<4;++k) at += x[k]*sm.Wxm[k*32+dj];
        }
        sm.attri_bf[dj*60 + n] = cvtbf(at);
      } else {
        int u = it - 1696;
        int i = u>>2, v = u&3, it2 = (i<NA)?0:1;
        const float* x = &sm.xin[i*16];
        float sacc; const float* uv;
        if (v < 2){ sacc = sm.ctxS[i][v];   uv = sm.uSrc[it2][v]; }
        else      { sacc = sm.ctxD[i][v-2]; uv = sm.uDst[it2][v-2]; }
        #pragma unroll
        for (int k=0;k<14;++k) sacc += x[k]*uv[k];
        if (v < 2) sm.srcv[i*2+v] = sacc; else sm.dstv[i*2+(v-2)] = sacc;
      }
    }
    __syncthreads();   // (B) attri_t, srcv, dstv ready

    // ---- ph3: masked softmax rows (4 lanes/row; e staged in LDS) ----
    if (tid < 212){
      int i = tid>>2, l = tid&3, it2 = (i<NA)?0:1;
      float s0 = sm.srcv[i*2+0], s1 = sm.srcv[i*2+1];
      float mx = -3.0e38f;
      for (int j=l; j<NN; j+=4){
        float e = ((j<NA)? s0 : s1) + sm.dstv[j*2+it2] + bfu(sm.biasE[i*56+j]);
        e = (e >= 0.f) ? e : 0.2f*e;
        sm.p[i*56+j] = e;
        mx = fmaxf(mx, e);
      }
      mx = fmaxf(mx, __shfl_xor(mx,1,64));
      mx = fmaxf(mx, __shfl_xor(mx,2,64));
      float sum = 0.f;
      for (int j=l; j<NN; j+=4){
        float pe = __expf(sm.p[i*56+j] - mx);
        sm.p[i*56+j] = pe;
        sum += pe;
      }
      sum += __shfl_xor(sum,1,64);
      sum += __shfl_xor(sum,2,64);
      if (l == 0) sm.inv[i] = 1.0f/sum;
    }
    __syncthreads();   // (C) p, inv ready

    // ---- ph4: gx = softmax @ attri -> bf16 into xh[:, 0:32) ----
    {
      const int nb = ng + 4*hs;   // rows nb, nb+8, ..., nb+48
      float c0=0.f,c1=0.f,c2=0.f,c3=0.f,c4=0.f,c5=0.f,c6=0.f;
      #pragma unroll
      for (int jc=0; jc<14; ++jc){
        uint2 ab = *(const uint2*)&sm.attri_bf[d*60 + jc*4];
        float a0=flo(ab.x), a1=fhi(ab.x), a2=flo(ab.y), a3=fhi(ab.y);
        const float* pc = &sm.p[jc*4];
        { float4 q=*(const float4*)&pc[(nb   )*56]; c0 += q.x*a0+q.y*a1+q.z*a2+q.w*a3; }
        { float4 q=*(const float4*)&pc[(nb+ 8)*56]; c1 += q.x*a0+q.y*a1+q.z*a2+q.w*a3; }
        { float4 q=*(const float4*)&pc[(nb+16)*56]; c2 += q.x*a0+q.y*a1+q.z*a2+q.w*a3; }
        { float4 q=*(const float4*)&pc[(nb+24)*56]; c3 += q.x*a0+q.y*a1+q.z*a2+q.w*a3; }
        { float4 q=*(const float4*)&pc[(nb+32)*56]; c4 += q.x*a0+q.y*a1+q.z*a2+q.w*a3; }
        { float4 q=*(const float4*)&pc[(nb+40)*56]; c5 += q.x*a0+q.y*a1+q.z*a2+q.w*a3; }
        if (nb+48 <= 52){ float4 q=*(const float4*)&pc[(nb+48)*56]; c6 += q.x*a0+q.y*a1+q.z*a2+q.w*a3; }
      }
      sm.xh[(nb   )*XHS + d] = cvtbf(c0*sm.inv[nb]);
      sm.xh[(nb+ 8)*XHS + d] = cvtbf(c1*sm.inv[nb+8]);
      sm.xh[(nb+16)*XHS + d] = cvtbf(c2*sm.inv[nb+16]);
      sm.xh[(nb+24)*XHS + d] = cvtbf(c3*sm.inv[nb+24]);
      sm.xh[(nb+32)*XHS + d] = cvtbf(c4*sm.inv[nb+32]);
      sm.xh[(nb+40)*XHS + d] = cvtbf(c5*sm.inv[nb+40]);
      if (nb+48 <= 52) sm.xh[(nb+48)*XHS + d] = cvtbf(c6*sm.inv[nb+48]);
    }
    __syncthreads();   // (D) xh x-part ready for all waves' A-fragments

    // ---- ph5: GRU via MFMA. D[53x128] = xh[53x64] @ B[64x128], epilogue elementwise ----
    {
      const bool last = (t == TT-1);
      auto run_pass = [&](int mt, int tp){
        const u16* xr = &sm.xh[(mt*16 + nl)*XHS + qd*8];
        s8v A0 = *(const s8v*)xr;          // k 0..31 (x)
        s8v A1 = *(const s8v*)(xr + 32);   // k 32..63 (h)
        f4v aR0={0,0,0,0}, aR1={0,0,0,0}, aZ0={0,0,0,0}, aZ1={0,0,0,0};
        f4v aI0={0,0,0,0}, aI1={0,0,0,0}, aG0={0,0,0,0}, aG1={0,0,0,0};
        aR0 = __builtin_amdgcn_mfma_f32_16x16x32_bf16(A0, bfr[0],  aR0, 0,0,0);
        aR0 = __builtin_amdgcn_mfma_f32_16x16x32_bf16(A1, bfr[1],  aR0, 0,0,0);
        aR1 = __builtin_amdgcn_mfma_f32_16x16x32_bf16(A0, bfr[2],  aR1, 0,0,0);
        aR1 = __builtin_amdgcn_mfma_f32_16x16x32_bf16(A1, bfr[3],  aR1, 0,0,0);
        aZ0 = __builtin_amdgcn_mfma_f32_16x16x32_bf16(A0, bfr[4],  aZ0, 0,0,0);
        aZ0 = __builtin_amdgcn_mfma_f32_16x16x32_bf16(A1, bfr[5],  aZ0, 0,0,0);
        aZ1 = __builtin_amdgcn_mfma_f32_16x16x32_bf16(A0, bfr[6],  aZ1, 0,0,0);
        aZ1 = __builtin_amdgcn_mfma_f32_16x16x32_bf16(A1, bfr[7],  aZ1, 0,0,0);
        aI0 = __builtin_amdgcn_mfma_f32_16x16x32_bf16(A0, bfr[8],  aI0, 0,0,0);
        aI0 = __builtin_amdgcn_mfma_f32_16x16x32_bf16(A1, bfr[9],  aI0, 0,0,0);
        aI1 = __builtin_amdgcn_mfma_f32_16x16x32_bf16(A0, bfr[10], aI1, 0,0,0);
        aI1 = __builtin_amdgcn_mfma_f32_16x16x32_bf16(A1, bfr[11], aI1, 0,0,0);
        aG0 = __builtin_amdgcn_mfma_f32_16x16x32_bf16(A0, bfr[12], aG0, 0,0,0);
        aG0 = __builtin_amdgcn_mfma_f32_16x16x32_bf16(A1, bfr[13], aG0, 0,0,0);
        aG1 = __builtin_amdgcn_mfma_f32_16x16x32_bf16(A0, bfr[14], aG1, 0,0,0);
        aG1 = __builtin_amdgcn_mfma_f32_16x16x32_bf16(A1, bfr[15], aG1, 0,0,0);
        const float* bi = tp ? sm.gb[2] : sm.gb[0];
        const float* bh = tp ? sm.gb[3] : sm.gb[1];
        const int d0 = nl, d1 = nl + 16;
        float br0=bi[d0]+bh[d0], bz0=bi[32+d0]+bh[32+d0], bn0=bi[64+d0], bg0=bh[64+d0];
        float br1=bi[d1]+bh[d1], bz1=bi[32+d1]+bh[32+d1], bn1=bi[64+d1], bg1=bh[64+d1];
        #pragma unroll
        for (int r=0;r<4;++r){
          int node = mt*16 + qd*4 + r;      // C/D layout: row=(lane>>4)*4+reg
          bool valid = tp ? (node>=NA && node<NN) : (node<NA);
          if (valid){
            float hold0 = sm.h[node*32+d0];
            float hold1 = sm.h[node*32+d1];
            float rr0 = 1.f/(1.f+__expf(-(aR0[r]+br0)));
            float zz0 = 1.f/(1.f+__expf(-(aZ0[r]+bz0)));
            float pr0 = (aI0[r]+bn0) + rr0*(aG0[r]+bg0);
            float e20 = __expf(2.f*pr0);
            float hn0 = (1.f-zz0)*(1.f-2.f/(e20+1.f)) + zz0*hold0;
            float rr1 = 1.f/(1.f+__expf(-(aR1[r]+br1)));
            float zz1 = 1.f/(1.f+__expf(-(aZ1[r]+bz1)));
            float pr1 = (aI1[r]+bn1) + rr1*(aG1[r]+bg1);
            float e21 = __expf(2.f*pr1);
            float hn1 = (1.f-zz1)*(1.f-2.f/(e21+1.f)) + zz1*hold1;
            sm.h[node*32+d0] = hn0;
            sm.h[node*32+d1] = hn1;
            sm.xh[node*XHS+32+d0] = cvtbf(hn0);
            sm.xh[node*XHS+32+d1] = cvtbf(hn1);
            if (last){
              long long oi = tp ? ((long long)OUT_MEO_BASE + (long long)b*(NM*HH) + (long long)(node-NA)*32)
                                : ((long long)b*(NA*HH) + (long long)node*32);
              if (isbf){ ((u16*)p.out)[oi+d0]=cvtbf(hn0); ((u16*)p.out)[oi+d1]=cvtbf(hn1); }
              else     { ((float*)p.out)[oi+d0]=hn0; ((float*)p.out)[oi+d1]=hn1; }
            }
          }
        }
      };
      if      (ng==0) run_pass(0,0);
      else if (ng==1) run_pass(1,0);
      else if (ng==2) run_pass(2,0);          // mixed tile, aqi rows 32-34
      else { run_pass(2,1); run_pass(3,1); }  // mixed tile meo rows 35-47; tile3 rows 48-52
    }
    // loop tail: epilogue h writes ordered vs next step's readers by barrier (A)
  }
}

extern "C" void kernel_launch(void* const* d_in, const int* in_sizes, int n_in,
                              void* d_out, int out_size, void* d_ws, size_t ws_size,
                              hipStream_t stream){
  (void)in_sizes; (void)n_in; (void)d_ws; (void)ws_size; (void)out_size;
  Params p;
  p.X_aqi = d_in[0];
  p.X_meo = d_in[1];
  p.ctx   = d_in[2];
  p.adj   = d_in[3];
  p.adjn  = d_in[4];
  p.emb0 = d_in[5];  p.emb1 = d_in[6];
  p.emb2 = d_in[7];  p.emb3 = d_in[8];
  p.emb4 = d_in[9];  p.emb5 = d_in[10];
  p.emb6 = d_in[11]; p.emb7 = d_in[12];
  p.emb8 = d_in[13];
  p.Wxa = d_in[14]; p.Wxm = d_in[15];
  p.Wua = d_in[16]; p.Wum = d_in[17];
  p.a0 = d_in[18]; p.a1 = d_in[19];
  p.a2 = d_in[20]; p.a3 = d_in[21];
  p.wih_a = d_in[22]; p.whh_a = d_in[23];
  p.bih_a = d_in[24]; p.bhh_a = d_in[25];
  p.wih_m = d_in[26]; p.whh_m = d_in[27];
  p.bih_m = d_in[28]; p.bhh_m = d_in[29];
  p.Xae = (const int*)d_in[30];
  p.Xme = (const int*)d_in[31];
  p.out = d_out;
  hipLaunchKernelGGL(chgat_gru_kernel, dim3(1024), dim3(256), 0, stream, p);
}